// Round 5
// baseline (57.041 us; speedup 1.0000x reference)
//
#include <hip/hip_runtime.h>

// per-profile targets (5 entries) and config multipliers (4 entries)
__device__ __constant__ float c_target_delay[5] = {2.0f, 1.0f, 0.5f, 5.0f, 3.0f};
__device__ __constant__ float c_target_pad[5]   = {0.08f, 0.12f, 0.05f, 0.15f, 0.10f};
__device__ __constant__ float c_config_mult[4]  = {1.0f, 1.3f, 1.6f, 2.0f};

// One WAVE per row (64 lanes x 32 elems = 2048). 4 rows per 256-thread block,
// grid = B/4 = 1024 blocks -> exactly 4096 waves, all co-resident (one
// dispatch round, no drain/refill bubble). No LDS, no __syncthreads.
// Lane 0 computes the full per-row loss contribution; kernel 2 is a 16KB sum.
__global__ __launch_bounds__(256, 4) void row_kernel(
    const int*   __restrict__ sizes,      // [B,S] int32
    const float* __restrict__ delays,     // [B,S] f32
    const int*   __restrict__ dirs,       // [B,S] int32
    const float* __restrict__ delay_ms,   // [B]
    const float* __restrict__ pad_norm,   // [B]
    const float* __restrict__ conf,       // [B]
    const int*   __restrict__ pids,       // [B]
    float*       __restrict__ partial,    // [B] per-row loss contribution
    int S, float inv_s_x100, float invB)
{
    const int lane = threadIdx.x & 63;
    const int row  = blockIdx.x * 4 + (threadIdx.x >> 6);
    const long long rowoff = (long long)row * (long long)S;

    const int*   srow = sizes  + rowoff;
    const float* drow = delays + rowoff;
    const int*   grow = dirs   + rowoff;

    const int base = lane * 32;             // 32 contiguous elems per lane

    const float pad = pad_norm[row];        // same addr across wave: 1 request
    const float dly = delay_ms[row];

    // prev element of this lane's span: raw elem base-1 (cache hit — the
    // neighboring lane streams that line). Lane 0 takes the row sentinel.
    float psz, pdr;
    if (lane == 0) { psz = -1.0f; pdr = -1.0f; }
    else {
        psz = (float)srow[base - 1];
        pdr = (float)grow[base - 1];
    }

    float sum = 0.0f;
    #pragma unroll
    for (int c = 0; c < 4; ++c) {
        const int cb = base + c * 8;
        int4   s0 = ((const int4*)(srow + cb))[0];
        int4   s1 = ((const int4*)(srow + cb))[1];
        float4 d0 = ((const float4*)(drow + cb))[0];
        float4 d1 = ((const float4*)(drow + cb))[1];
        int4   g0 = ((const int4*)(grow + cb))[0];
        int4   g1 = ((const int4*)(grow + cb))[1];

        float sz[8] = {(float)s0.x, (float)s0.y, (float)s0.z, (float)s0.w,
                       (float)s1.x, (float)s1.y, (float)s1.z, (float)s1.w};
        float dl[8] = {d0.x, d0.y, d0.z, d0.w, d1.x, d1.y, d1.z, d1.w};
        float dr[8] = {(float)g0.x, (float)g0.y, (float)g0.z, (float)g0.w,
                       (float)g1.x, (float)g1.y, (float)g1.z, (float)g1.w};

        // last-packet morphing: elem S-1 only (lane 63, chunk 3). The morphed
        // value is never used as a "prev" (reference shifts pre-morph columns,
        // and elem S-1 is the last). Carry psz/pdr stay raw.
        if (c == 3 && lane == 63) {
            sz[7] = fminf(sz[7] + pad * 1500.0f, 1500.0f);
            dl[7] = dl[7] + dly;
        }

        #pragma unroll
        for (int j = 0; j < 8; ++j) {
            float inc = 0.0f;
            inc += (sz[j] > 1400.0f)           ? 0.6f : 0.0f;
            inc += (dl[j] < 0.05f)             ? 0.4f : 0.0f;
            inc += (fabsf(sz[j] - psz) < 0.5f) ? 0.2f : 0.0f;
            inc += (dr[j] != pdr)              ? 0.1f : 0.0f;
            sum += inc;
            psz = sz[j];
            pdr = dr[j];
        }
    }

    // wave-local reduce only — no cross-wave communication anywhere
    #pragma unroll
    for (int off = 32; off > 0; off >>= 1)
        sum += __shfl_down(sum, off, 64);

    if (lane == 0) {
        const int pid = pids[row];
        const float score = sum * inv_s_x100 * c_config_mult[pid & 3];

        float v = 0.0f;
        v += (2.0f / 30.0f) * fmaxf(score - 15.0f, 0.0f);                 // DPI
        v += 0.5f * (fabsf(dly - c_target_delay[pid]) +
                     fabsf(pad - c_target_pad[pid]));                      // similarity
        v += (0.3f / 20.0f) * fmaxf(dly - 20.0f, 0.0f);                   // efficiency (delay)
        v += 0.3f * fmaxf(pad - 0.3f, 0.0f);                              // efficiency (pad)
        const float ev = (score < 30.0f) ? 1.0f : 0.0f;
        const float cc = conf[row] - ev;
        v += 0.2f * cc * cc;                                               // confidence

        partial[row] = v * invB;
    }
}

// Single block: pure sum of B per-row contributions (16 KB read).
__global__ __launch_bounds__(1024) void final_kernel(
    const float* __restrict__ partial, float* __restrict__ out, int B)
{
    const int tid = threadIdx.x;
    float s = 0.0f;
    for (int i = tid; i < (B >> 2); i += 1024) {
        float4 p = ((const float4*)partial)[i];
        s += (p.x + p.y) + (p.z + p.w);
    }

    #pragma unroll
    for (int off = 32; off > 0; off >>= 1)
        s += __shfl_down(s, off, 64);

    __shared__ float wsum[1024 / 64];
    if ((tid & 63) == 0) wsum[tid >> 6] = s;
    __syncthreads();

    if (tid == 0) {
        float tot = 0.0f;
        #pragma unroll
        for (int w = 0; w < 1024 / 64; ++w) tot += wsum[w];
        out[0] = tot;
    }
}

extern "C" void kernel_launch(void* const* d_in, const int* in_sizes, int n_in,
                              void* d_out, int out_size, void* d_ws, size_t ws_size,
                              hipStream_t stream) {
    const int*   sizes    = (const int*)  d_in[0];
    const float* delays   = (const float*)d_in[1];
    const int*   dirs     = (const int*)  d_in[2];
    const float* delay_ms = (const float*)d_in[3];
    const float* pad_norm = (const float*)d_in[4];
    const float* conf     = (const float*)d_in[5];
    const int*   pids     = (const int*)  d_in[6];
    float* out = (float*)d_out;

    const int B = in_sizes[3];                 // 4096
    const int S = in_sizes[0] / B;             // 2048

    float* partial = (float*)d_ws;             // B floats of scratch

    row_kernel<<<B / 4, 256, 0, stream>>>(
        sizes, delays, dirs, delay_ms, pad_norm, conf, pids,
        partial, S, 100.0f / (float)S, 1.0f / (float)B);

    final_kernel<<<1, 1024, 0, stream>>>(partial, out, B);
}

// Round 6
// 24.784 us; speedup vs baseline: 2.3015x; 2.3015x over previous
//
#include <hip/hip_runtime.h>

#define BLOCK 256

// per-profile targets (5 entries) and config multipliers (4 entries)
__device__ __constant__ float c_target_delay[5] = {2.0f, 1.0f, 0.5f, 5.0f, 3.0f};
__device__ __constant__ float c_target_pad[5]   = {0.08f, 0.12f, 0.05f, 0.15f, 0.10f};
__device__ __constant__ float c_config_mult[4]  = {1.0f, 1.3f, 1.6f, 2.0f};

// R4 structure (proven 24.7us) + 2 rows per block:
// grid = B/2 = 2048 blocks x 4 waves = 8192 waves = exactly one dispatch
// round (32 waves/CU at VGPR<=64). Each wave independently owns a 512-elem
// segment; no LDS, no __syncthreads, no block epilogue. The unrolled second
// row overlaps its loads with the first row's reduce.
__global__ __launch_bounds__(BLOCK) void seg2_kernel(
    const int*   __restrict__ sizes,      // [B,S] int32
    const float* __restrict__ delays,     // [B,S] f32
    const int*   __restrict__ dirs,       // [B,S] int32
    const float* __restrict__ delay_ms,   // [B]
    const float* __restrict__ pad_norm,   // [B]
    float*       __restrict__ partial,    // [B*4] per-segment inc sums
    int S)
{
    const int lane = threadIdx.x & 63;
    const int seg  = threadIdx.x >> 6;          // 0..3
    const int segbase = seg * 512;              // S == 4*512
    const int base = segbase + lane * 8;        // lane stride 32B: coalesced

    #pragma unroll
    for (int rr = 0; rr < 2; ++rr) {
        const int row = blockIdx.x * 2 + rr;
        const long long rowoff = (long long)row * (long long)S;

        const int*   srow = sizes  + rowoff;
        const float* drow = delays + rowoff;
        const int*   grow = dirs   + rowoff;

        // 6 coalesced 16B loads per thread
        int4   s0 = ((const int4*)(srow + base))[0];
        int4   s1 = ((const int4*)(srow + base))[1];
        float4 d0 = ((const float4*)(drow + base))[0];
        float4 d1 = ((const float4*)(drow + base))[1];
        int4   g0 = ((const int4*)(grow + base))[0];
        int4   g1 = ((const int4*)(grow + base))[1];

        float sz[8] = {(float)s0.x, (float)s0.y, (float)s0.z, (float)s0.w,
                       (float)s1.x, (float)s1.y, (float)s1.z, (float)s1.w};
        float dl[8] = {d0.x, d0.y, d0.z, d0.w, d1.x, d1.y, d1.z, d1.w};
        float dr[8] = {(float)g0.x, (float)g0.y, (float)g0.z, (float)g0.w,
                       (float)g1.x, (float)g1.y, (float)g1.z, (float)g1.w};

        // prev of this thread's chunk: previous lane's last raw element;
        // lane 0 reads the segment-boundary element (cache hit) or sentinel.
        float psz = __shfl_up(sz[7], 1, 64);
        float pdr = __shfl_up(dr[7], 1, 64);
        if (lane == 0) {
            if (seg == 0) { psz = -1.0f; pdr = -1.0f; }
            else {
                psz = (float)srow[segbase - 1];
                pdr = (float)grow[segbase - 1];
            }
        }

        // last-packet morphing: only elem S-1 (seg 3, lane 63). Morphed value
        // is never used as a "prev" (reference shifts pre-morph columns).
        if (seg == 3 && lane == 63) {
            sz[7] = fminf(sz[7] + pad_norm[row] * 1500.0f, 1500.0f);
            dl[7] = dl[7] + delay_ms[row];
        }

        float sum = 0.0f;
        #pragma unroll
        for (int j = 0; j < 8; ++j) {
            float inc = 0.0f;
            inc += (sz[j] > 1400.0f)           ? 0.6f : 0.0f;
            inc += (dl[j] < 0.05f)             ? 0.4f : 0.0f;
            inc += (fabsf(sz[j] - psz) < 0.5f) ? 0.2f : 0.0f;
            inc += (dr[j] != pdr)              ? 0.1f : 0.0f;
            sum += inc;
            psz = sz[j];
            pdr = dr[j];
        }

        // wave-local reduce; no cross-wave communication
        #pragma unroll
        for (int off = 32; off > 0; off >>= 1)
            sum += __shfl_down(sum, off, 64);

        if (lane == 0) partial[row * 4 + seg] = sum;
    }
}

// Single block: fold 4 partials per row, apply per-row score math, reduce.
__global__ __launch_bounds__(1024) void final_kernel(
    const float* __restrict__ partial,    // [B*4]
    const float* __restrict__ delay_ms,   // [B]
    const float* __restrict__ pad_norm,   // [B]
    const float* __restrict__ conf,       // [B]
    const int*   __restrict__ pids,       // [B]
    float*       __restrict__ out,        // [1]
    int B, float inv_s_x100, float invB)
{
    const int tid = threadIdx.x;
    float s = 0.0f;

    for (int r = tid; r < B; r += 1024) {
        float4 p = ((const float4*)partial)[r];
        const float tot = (p.x + p.y) + (p.z + p.w);

        const int   pid = pids[r];
        const float dly = delay_ms[r];
        const float pad = pad_norm[r];
        const float score = tot * inv_s_x100 * c_config_mult[pid & 3];

        float v = 0.0f;
        v += (2.0f / 30.0f) * fmaxf(score - 15.0f, 0.0f);                 // DPI
        v += 0.5f * (fabsf(dly - c_target_delay[pid]) +
                     fabsf(pad - c_target_pad[pid]));                      // similarity
        v += (0.3f / 20.0f) * fmaxf(dly - 20.0f, 0.0f);                   // efficiency (delay)
        v += 0.3f * fmaxf(pad - 0.3f, 0.0f);                              // efficiency (pad)
        const float ev = (score < 30.0f) ? 1.0f : 0.0f;
        const float c  = conf[r] - ev;
        v += 0.2f * c * c;                                                 // confidence

        s += v * invB;
    }

    #pragma unroll
    for (int off = 32; off > 0; off >>= 1)
        s += __shfl_down(s, off, 64);

    __shared__ float wsum[1024 / 64];
    if ((tid & 63) == 0) wsum[tid >> 6] = s;
    __syncthreads();

    if (tid == 0) {
        float tot = 0.0f;
        #pragma unroll
        for (int w = 0; w < 1024 / 64; ++w) tot += wsum[w];
        out[0] = tot;
    }
}

extern "C" void kernel_launch(void* const* d_in, const int* in_sizes, int n_in,
                              void* d_out, int out_size, void* d_ws, size_t ws_size,
                              hipStream_t stream) {
    const int*   sizes    = (const int*)  d_in[0];
    const float* delays   = (const float*)d_in[1];
    const int*   dirs     = (const int*)  d_in[2];
    const float* delay_ms = (const float*)d_in[3];
    const float* pad_norm = (const float*)d_in[4];
    const float* conf     = (const float*)d_in[5];
    const int*   pids     = (const int*)  d_in[6];
    float* out = (float*)d_out;

    const int B = in_sizes[3];                 // 4096
    const int S = in_sizes[0] / B;             // 2048

    float* partial = (float*)d_ws;             // B*4 floats of scratch

    seg2_kernel<<<B / 2, BLOCK, 0, stream>>>(
        sizes, delays, dirs, delay_ms, pad_norm, partial, S);

    final_kernel<<<1, 1024, 0, stream>>>(
        partial, delay_ms, pad_norm, conf, pids, out,
        B, 100.0f / (float)S, 1.0f / (float)B);
}